// Round 2
// baseline (712.447 us; speedup 1.0000x reference)
//
#include <hip/hip_runtime.h>
#include <hip/hip_bf16.h>
#include <stdint.h>

#define IN_F 4096
#define OUT_F 4096
#define NOUT 40
#define KPAD 4160   // 4096 + 64 (40 outlier cols + 24 zero pad)
#define M_TOT 8192  // 4*2048

#define BM 128
#define BN 128
#define BK 32

typedef float f32x4 __attribute__((ext_vector_type(4)));
typedef __bf16 bf16x8 __attribute__((ext_vector_type(8)));

typedef __attribute__((address_space(1))) void GV;
typedef __attribute__((address_space(3))) void LV;
#define GLDS16(gp, lp) \
  __builtin_amdgcn_global_load_lds((GV*)(gp), (LV*)(lp), 16, 0, 0)

__device__ __forceinline__ unsigned short f2bf(float f) {
  // round-to-nearest-even bf16 (finite values only here)
  unsigned u = __float_as_uint(f);
  u += 0x7FFFu + ((u >> 16) & 1u);
  return (unsigned short)(u >> 16);
}

// ---- mask build: mask[c]=1 except outlier channels ----
__global__ void k_mask_init(float* mask) {
  mask[blockIdx.x * 256 + threadIdx.x] = 1.0f;
}
__global__ void k_mask_zero(float* mask, const int* __restrict__ oidx) {
  if (threadIdx.x < NOUT) mask[oidx[threadIdx.x]] = 0.0f;
}

// ---- masked global abs-max over x (fp32) ----
__global__ void k_absmax(const float4* __restrict__ x4, const float4* __restrict__ mask4,
                         unsigned* __restrict__ out) {
  const int n4 = M_TOT * IN_F / 4;
  float m = 0.f;
  const int stride = gridDim.x * blockDim.x;
  for (int i = blockIdx.x * blockDim.x + threadIdx.x; i < n4; i += stride) {
    float4 u = x4[i];
    float4 mk = mask4[i & 1023];  // column group (i*4) % 4096, /4
    m = fmaxf(m, fabsf(u.x) * mk.x);
    m = fmaxf(m, fabsf(u.y) * mk.y);
    m = fmaxf(m, fabsf(u.z) * mk.z);
    m = fmaxf(m, fabsf(u.w) * mk.w);
  }
#pragma unroll
  for (int off = 32; off; off >>= 1) m = fmaxf(m, __shfl_down(m, off, 64));
  if ((threadIdx.x & 63) == 0) atomicMax(out, __float_as_uint(m));
}

// ---- A' = [rint(clip(x)*127/upper) | (x - clip(x))*127/upper on outlier cols | 0] ----
// bf16 [M_TOT][KPAD]; integer part exactly representable in bf16.
__global__ void k_prep_a(const float* __restrict__ x,
                         const int* __restrict__ oidx,
                         const unsigned* __restrict__ upper_bits,
                         unsigned short* __restrict__ A) {
  const int m = blockIdx.x;
  const int t = threadIdx.x;
  const float upper = __uint_as_float(*upper_bits);
  const float inv = 127.0f / fmaxf(upper, 1e-5f);
  const float4* xr = (const float4*)(x + (size_t)m * IN_F);
  uint4* Ar = (uint4*)(A + (size_t)m * KPAD);  // row base: 8320 B, 16B aligned
#pragma unroll
  for (int rep = 0; rep < 2; ++rep) {
    const int c = t + rep * 256;  // 512 groups of 8 floats per row
    float4 u0 = xr[2 * c];
    float4 u1 = xr[2 * c + 1];
    float f[8] = {u0.x, u0.y, u0.z, u0.w, u1.x, u1.y, u1.z, u1.w};
    unsigned o[4];
#pragma unroll
    for (int w = 0; w < 4; ++w) {
      float a = fminf(fmaxf(f[2 * w], -upper), upper);
      float b = fminf(fmaxf(f[2 * w + 1], -upper), upper);
      unsigned short b0 = f2bf(rintf(a * inv));
      unsigned short b1 = f2bf(rintf(b * inv));
      o[w] = (unsigned)b0 | ((unsigned)b1 << 16);
    }
    uint4 ov; ov.x = o[0]; ov.y = o[1]; ov.z = o[2]; ov.w = o[3];
    Ar[c] = ov;
  }
  if (t < 64) {
    unsigned short v = 0;
    if (t < NOUT) {
      float xf = x[(size_t)m * IN_F + oidx[t]];
      float xc = fminf(fmaxf(xf, -upper), upper);
      v = f2bf((xf - xc) * inv);  // residual pre-divided by scale
    }
    A[(size_t)m * KPAD + IN_F + t] = v;
  }
}

// ---- W' = [W | B | 0] as bf16 [OUT_F][KPAD] ----
__global__ void k_prep_w(const float* __restrict__ w, const float* __restrict__ Bm,
                         unsigned short* __restrict__ W) {
  const int o = blockIdx.x;
  const int t = threadIdx.x;
  const float4* wr = (const float4*)(w + (size_t)o * IN_F);
  uint4* Wr = (uint4*)(W + (size_t)o * KPAD);
#pragma unroll
  for (int rep = 0; rep < 2; ++rep) {
    const int c = t + rep * 256;
    float4 u0 = wr[2 * c];
    float4 u1 = wr[2 * c + 1];
    uint4 ov;
    ov.x = (unsigned)f2bf(u0.x) | ((unsigned)f2bf(u0.y) << 16);
    ov.y = (unsigned)f2bf(u0.z) | ((unsigned)f2bf(u0.w) << 16);
    ov.z = (unsigned)f2bf(u1.x) | ((unsigned)f2bf(u1.y) << 16);
    ov.w = (unsigned)f2bf(u1.z) | ((unsigned)f2bf(u1.w) << 16);
    Wr[c] = ov;
  }
  if (t < 64)
    W[(size_t)o * KPAD + IN_F + t] =
        (t < NOUT) ? f2bf(Bm[(size_t)o * NOUT + t]) : (unsigned short)0;
}

// ---- main GEMM: out[m][n] = scale * sum_k A'[m][k] W'[n][k] + bias[n] (fp32 out) ----
__global__ __launch_bounds__(256) void k_gemm(
    const unsigned short* __restrict__ A, const unsigned short* __restrict__ W,
    const float* __restrict__ bias, const unsigned* __restrict__ upper_bits,
    float* __restrict__ out) {
  __shared__ __attribute__((aligned(16))) unsigned short As[BM * BK];
  __shared__ __attribute__((aligned(16))) unsigned short Ws[BN * BK];
  const int t = threadIdx.x;
  const int bm = (int)(blockIdx.x >> 5) * BM;  // N-fastest: 32 consecutive blocks share A tile
  const int bn = (int)(blockIdx.x & 31) * BN;
  const int lane = t & 63;
  const int wave = t >> 6;
  const int wm = (wave >> 1) * 64, wn = (wave & 1) * 64;
  const int lrow = lane & 15, lquad = lane >> 4;

  f32x4 acc[4][4] = {};

  // staging: thread t loads 16 B at tile-row t/4, k-offset (t&3)*8
  const unsigned short* Ag = A + (size_t)(bm + (t >> 2)) * KPAD + (t & 3) * 8;
  const unsigned short* Wg = W + (size_t)(bn + (t >> 2)) * KPAD + (t & 3) * 8;
  char* ldsA = (char*)As + t * 16;  // wave-uniform base + lane*16: contiguous
  char* ldsW = (char*)Ws + t * 16;
  const size_t rstep = (size_t)64 * KPAD;

  for (int k0 = 0; k0 < KPAD; k0 += BK) {  // 130 iters
    GLDS16(Ag + k0, ldsA);
    GLDS16(Ag + rstep + k0, ldsA + 4096);
    GLDS16(Wg + k0, ldsW);
    GLDS16(Wg + rstep + k0, ldsW + 4096);
    __syncthreads();
    bf16x8 av[4], bv[4];
#pragma unroll
    for (int i = 0; i < 4; ++i)
      av[i] = *(const bf16x8*)(As + (wm + i * 16 + lrow) * BK + lquad * 8);
#pragma unroll
    for (int j = 0; j < 4; ++j)
      bv[j] = *(const bf16x8*)(Ws + (wn + j * 16 + lrow) * BK + lquad * 8);
#pragma unroll
    for (int i = 0; i < 4; ++i)
#pragma unroll
      for (int j = 0; j < 4; ++j)
        acc[i][j] = __builtin_amdgcn_mfma_f32_16x16x32_bf16(av[i], bv[j], acc[i][j], 0, 0, 0);
    __syncthreads();
  }

  const float scale = fmaxf(__uint_as_float(*upper_bits), 1e-5f) * (1.0f / 127.0f);
#pragma unroll
  for (int i = 0; i < 4; ++i) {
    const int row = bm + wm + i * 16 + lquad * 4;  // C/D: row = quad*4 + reg
#pragma unroll
    for (int j = 0; j < 4; ++j) {
      const int col = bn + wn + j * 16 + lrow;     // C/D: col = lane & 15
      const float bs = bias[col];
#pragma unroll
      for (int r = 0; r < 4; ++r)
        out[(size_t)(row + r) * OUT_F + col] = scale * acc[i][j][r] + bs;
    }
  }
}

extern "C" void kernel_launch(void* const* d_in, const int* in_sizes, int n_in,
                              void* d_out, int out_size, void* d_ws, size_t ws_size,
                              hipStream_t stream) {
  (void)in_sizes; (void)n_in; (void)out_size; (void)ws_size;
  const float* x    = (const float*)d_in[0];  // fp32 [4,2048,4096]
  const float* w    = (const float*)d_in[1];  // fp32 [4096,4096]
  const float* B    = (const float*)d_in[2];  // fp32 [4096,40]
  const float* bias = (const float*)d_in[3];  // fp32 [1,4096]
  const int* oidx   = (const int*)d_in[4];    // int32 [40]
  float* out = (float*)d_out;                 // fp32 [4,2048,4096]

  char* ws = (char*)d_ws;
  unsigned* upper = (unsigned*)ws;                     // 4 B atomic slot
  float* mask = (float*)(ws + 256);                    // 16 KB
  unsigned short* Ap = (unsigned short*)(ws + 65536);  // 8192*4160*2 = 68 MB
  unsigned short* Wp = Ap + (size_t)M_TOT * KPAD;      // 4096*4160*2 = 34 MB

  hipMemsetAsync(upper, 0, 4, stream);
  k_mask_init<<<16, 256, 0, stream>>>(mask);
  k_mask_zero<<<1, 64, 0, stream>>>(mask, oidx);
  k_absmax<<<2048, 256, 0, stream>>>((const float4*)x, (const float4*)mask, upper);
  k_prep_a<<<M_TOT, 256, 0, stream>>>(x, oidx, upper, Ap);
  k_prep_w<<<OUT_F, 256, 0, stream>>>(w, B, Wp);
  k_gemm<<<(M_TOT / BM) * (OUT_F / BN), 256, 0, stream>>>(Ap, Wp, bias, upper, out);
}

// Round 3
// 699.265 us; speedup vs baseline: 1.0189x; 1.0189x over previous
//
#include <hip/hip_runtime.h>
#include <hip/hip_bf16.h>
#include <stdint.h>

#define IN_F 4096
#define OUT_F 4096
#define NOUT 40
#define KPAD 4160   // 4096 + 64 (40 outlier cols + 24 zero pad)
#define M_TOT 8192  // 4*2048

#define BM 128
#define BN 128
#define BK 32

typedef float f32x4 __attribute__((ext_vector_type(4)));
typedef __bf16 bf16x8 __attribute__((ext_vector_type(8)));

typedef __attribute__((address_space(1))) void GV;
typedef __attribute__((address_space(3))) void LV;
#define GLDS16(gp, lp) \
  __builtin_amdgcn_global_load_lds((GV*)(gp), (LV*)(lp), 16, 0, 0)

__device__ __forceinline__ unsigned short f2bf(float f) {
  unsigned u = __float_as_uint(f);
  u += 0x7FFFu + ((u >> 16) & 1u);
  return (unsigned short)(u >> 16);
}

// ---- masked global abs-max over x (fp32), outlier mask as LDS bitmap ----
__global__ void k_absmax(const float4* __restrict__ x4, const int* __restrict__ oidx,
                         unsigned* __restrict__ out) {
  __shared__ unsigned bits[128];  // 4096-bit outlier-channel mask
  const int t = threadIdx.x;
  if (t < 128) bits[t] = 0;
  __syncthreads();
  if (t < NOUT) {
    int c = oidx[t];
    atomicOr(&bits[c >> 5], 1u << (c & 31));
  }
  __syncthreads();
  const int n4 = M_TOT * IN_F / 4;
  float m = 0.f;
  const int stride = gridDim.x * blockDim.x;
  for (int i = blockIdx.x * blockDim.x + t; i < n4; i += stride) {
    float4 u = x4[i];
    unsigned wb = bits[(i & 1023) >> 3];  // word for columns (i*4 .. i*4+3) % 4096
    int sh = (i & 7) * 4;
    m = fmaxf(m, ((wb >> (sh + 0)) & 1) ? 0.f : fabsf(u.x));
    m = fmaxf(m, ((wb >> (sh + 1)) & 1) ? 0.f : fabsf(u.y));
    m = fmaxf(m, ((wb >> (sh + 2)) & 1) ? 0.f : fabsf(u.z));
    m = fmaxf(m, ((wb >> (sh + 3)) & 1) ? 0.f : fabsf(u.w));
  }
#pragma unroll
  for (int off = 32; off; off >>= 1) m = fmaxf(m, __shfl_down(m, off, 64));
  if ((t & 63) == 0) atomicMax(out, __float_as_uint(m));
}

// ---- A' = [rint(clip(x)*127/upper) | (x - clip(x))*127/upper on outlier cols | 0] ----
__global__ void k_prep_a(const float* __restrict__ x,
                         const int* __restrict__ oidx,
                         const unsigned* __restrict__ upper_bits,
                         unsigned short* __restrict__ A) {
  const int m = blockIdx.x;
  const int t = threadIdx.x;
  const float upper = __uint_as_float(*upper_bits);
  const float inv = 127.0f / fmaxf(upper, 1e-5f);
  const float4* xr = (const float4*)(x + (size_t)m * IN_F);
  uint4* Ar = (uint4*)(A + (size_t)m * KPAD);
#pragma unroll
  for (int rep = 0; rep < 2; ++rep) {
    const int c = t + rep * 256;
    float4 u0 = xr[2 * c];
    float4 u1 = xr[2 * c + 1];
    float f[8] = {u0.x, u0.y, u0.z, u0.w, u1.x, u1.y, u1.z, u1.w};
    unsigned o[4];
#pragma unroll
    for (int w = 0; w < 4; ++w) {
      float a = fminf(fmaxf(f[2 * w], -upper), upper);
      float b = fminf(fmaxf(f[2 * w + 1], -upper), upper);
      unsigned short b0 = f2bf(rintf(a * inv));
      unsigned short b1 = f2bf(rintf(b * inv));
      o[w] = (unsigned)b0 | ((unsigned)b1 << 16);
    }
    uint4 ov; ov.x = o[0]; ov.y = o[1]; ov.z = o[2]; ov.w = o[3];
    Ar[c] = ov;
  }
  if (t < 64) {
    unsigned short v = 0;
    if (t < NOUT) {
      float xf = x[(size_t)m * IN_F + oidx[t]];
      float xc = fminf(fmaxf(xf, -upper), upper);
      v = f2bf((xf - xc) * inv);
    }
    A[(size_t)m * KPAD + IN_F + t] = v;
  }
}

// ---- W' = [W | B | 0] as bf16 [OUT_F][KPAD] ----
__global__ void k_prep_w(const float* __restrict__ w, const float* __restrict__ Bm,
                         unsigned short* __restrict__ W) {
  const int o = blockIdx.x;
  const int t = threadIdx.x;
  const float4* wr = (const float4*)(w + (size_t)o * IN_F);
  uint4* Wr = (uint4*)(W + (size_t)o * KPAD);
#pragma unroll
  for (int rep = 0; rep < 2; ++rep) {
    const int c = t + rep * 256;
    float4 u0 = wr[2 * c];
    float4 u1 = wr[2 * c + 1];
    uint4 ov;
    ov.x = (unsigned)f2bf(u0.x) | ((unsigned)f2bf(u0.y) << 16);
    ov.y = (unsigned)f2bf(u0.z) | ((unsigned)f2bf(u0.w) << 16);
    ov.z = (unsigned)f2bf(u1.x) | ((unsigned)f2bf(u1.y) << 16);
    ov.w = (unsigned)f2bf(u1.z) | ((unsigned)f2bf(u1.w) << 16);
    Wr[c] = ov;
  }
  if (t < 64)
    W[(size_t)o * KPAD + IN_F + t] =
        (t < NOUT) ? f2bf(Bm[(size_t)o * NOUT + t]) : (unsigned short)0;
}

// ---- main GEMM with XOR-swizzled LDS (conflict-free ds_read_b128) ----
// LDS slot (row r, kgroup q') holds global kgroup q = q' ^ sigma(r), sigma(r)=(r>>1)&3.
__global__ __launch_bounds__(256) void k_gemm(
    const unsigned short* __restrict__ A, const unsigned short* __restrict__ W,
    const float* __restrict__ bias, const unsigned* __restrict__ upper_bits,
    float* __restrict__ out) {
  __shared__ __attribute__((aligned(16))) unsigned short As[BM * BK];
  __shared__ __attribute__((aligned(16))) unsigned short Ws[BN * BK];
  const int t = threadIdx.x;
  const int bm = (int)(blockIdx.x >> 5) * BM;  // N-fastest: 32 blocks share A tile
  const int bn = (int)(blockIdx.x & 31) * BN;
  const int lane = t & 63;
  const int wave = t >> 6;
  const int wm = (wave >> 1) * 64, wn = (wave & 1) * 64;
  const int lrow = lane & 15, lquad = lane >> 4;

  f32x4 acc[4][4] = {};

  // staging: thread t stages tile-row t>>2; fetches swizzled k-group (t&3)^sigma(t>>2)
  const int kswz = ((t & 3) ^ ((t >> 3) & 3)) * 8;
  const unsigned short* Ag = A + (size_t)(bm + (t >> 2)) * KPAD + kswz;
  const unsigned short* Wg = W + (size_t)(bn + (t >> 2)) * KPAD + kswz;
  char* ldsA = (char*)As + t * 16;
  char* ldsW = (char*)Ws + t * 16;
  const size_t rstep = (size_t)64 * KPAD;

  // fragment read: k-group lquad lives at slot lquad ^ sigma(row), sigma=(lrow>>1)&3
  const int qsA = (lquad ^ ((lrow >> 1) & 3)) * 8;

  for (int k0 = 0; k0 < KPAD; k0 += BK) {  // 130 iters
    GLDS16(Ag + k0, ldsA);
    GLDS16(Ag + rstep + k0, ldsA + 4096);
    GLDS16(Wg + k0, ldsW);
    GLDS16(Wg + rstep + k0, ldsW + 4096);
    __syncthreads();
    bf16x8 av[4], bv[4];
#pragma unroll
    for (int i = 0; i < 4; ++i)
      av[i] = *(const bf16x8*)(As + (wm + i * 16 + lrow) * BK + qsA);
#pragma unroll
    for (int j = 0; j < 4; ++j)
      bv[j] = *(const bf16x8*)(Ws + (wn + j * 16 + lrow) * BK + qsA);
#pragma unroll
    for (int i = 0; i < 4; ++i)
#pragma unroll
      for (int j = 0; j < 4; ++j)
        acc[i][j] = __builtin_amdgcn_mfma_f32_16x16x32_bf16(av[i], bv[j], acc[i][j], 0, 0, 0);
    __syncthreads();
  }

  const float scale = fmaxf(__uint_as_float(*upper_bits), 1e-5f) * (1.0f / 127.0f);
#pragma unroll
  for (int i = 0; i < 4; ++i) {
    const int row = bm + wm + i * 16 + lquad * 4;  // C/D: row = quad*4 + reg
#pragma unroll
    for (int j = 0; j < 4; ++j) {
      const int col = bn + wn + j * 16 + lrow;     // C/D: col = lane & 15
      const float bs = bias[col];
#pragma unroll
      for (int r = 0; r < 4; ++r)
        out[(size_t)(row + r) * OUT_F + col] = scale * acc[i][j][r] + bs;
    }
  }
}

extern "C" void kernel_launch(void* const* d_in, const int* in_sizes, int n_in,
                              void* d_out, int out_size, void* d_ws, size_t ws_size,
                              hipStream_t stream) {
  (void)in_sizes; (void)n_in; (void)out_size; (void)ws_size;
  const float* x    = (const float*)d_in[0];  // fp32 [4,2048,4096]
  const float* w    = (const float*)d_in[1];  // fp32 [4096,4096]
  const float* B    = (const float*)d_in[2];  // fp32 [4096,40]
  const float* bias = (const float*)d_in[3];  // fp32 [1,4096]
  const int* oidx   = (const int*)d_in[4];    // int32 [40]
  float* out = (float*)d_out;                 // fp32 [4,2048,4096]

  char* ws = (char*)d_ws;
  unsigned* upper = (unsigned*)ws;                     // 4 B atomic slot
  unsigned short* Ap = (unsigned short*)(ws + 65536);  // 8192*4160*2 = 68 MB
  unsigned short* Wp = Ap + (size_t)M_TOT * KPAD;      // 4096*4160*2 = 34 MB

  hipMemsetAsync(upper, 0, 4, stream);
  k_absmax<<<2048, 256, 0, stream>>>((const float4*)x, oidx, upper);
  k_prep_a<<<M_TOT, 256, 0, stream>>>(x, oidx, upper, Ap);
  k_prep_w<<<OUT_F, 256, 0, stream>>>(w, B, Wp);
  k_gemm<<<(M_TOT / BM) * (OUT_F / BN), 256, 0, stream>>>(Ap, Wp, bias, upper, out);
}